// Round 5
// baseline (1134.807 us; speedup 1.0000x reference)
//
#include <hip/hip_runtime.h>
#include <stdint.h>

typedef unsigned short u16;
typedef unsigned int u32;
typedef __attribute__((ext_vector_type(8))) short short8;   // 8 x bf16 (4 VGPRs)
typedef __attribute__((ext_vector_type(4))) float f32x4;

#define DEVI static __device__ __forceinline__

#define S_LEN 2048
#define DMODEL 1024
#define NHEAD 16
#define DK 64
#define NEG_INF (-__builtin_inff())
// u = bitcast((bits>>9)|0x3f800000)-1; boundary 0.9f = 7549747/2^23
// keep:   u > 0.9  <=> bits >= 7549748*512
// dropout keep: u < 0.9  <=> bits <  7549747*512
#define KEEPC 3865470976u
#define DROPC 3865470464u

DEVI u16 f2bf(float f) {
  u32 u = __builtin_bit_cast(u32, f);
  u32 r = u + 0x7fffu + ((u >> 16) & 1u);   // RNE
  return (u16)(r >> 16);
}

DEVI short8 cvt8(float4 a, float4 b) {
  short8 r;
  r[0] = (short)f2bf(a.x); r[1] = (short)f2bf(a.y);
  r[2] = (short)f2bf(a.z); r[3] = (short)f2bf(a.w);
  r[4] = (short)f2bf(b.x); r[5] = (short)f2bf(b.y);
  r[6] = (short)f2bf(b.z); r[7] = (short)f2bf(b.w);
  return r;
}

// JAX threefry2x32 (20 rounds), partitionable draw (default since jax 0.4.36):
// key (0,key), ctr (0,i), bits = o0 ^ o1. key is compile-time const at call
// sites -> K2 and injections fold. Validated bit-exact in rounds 2/3.
DEVI u32 tf_bits(u32 key, u32 i) {
  const u32 K2 = key ^ 0x1BD11BDAu;
  u32 x0 = 0u, x1 = i + key;
#define TFR(r) { x0 += x1; x1 = __builtin_rotateleft32(x1, r); x1 ^= x0; }
  TFR(13) TFR(15) TFR(26) TFR(6)  x0 += key; x1 += K2 + 1u;
  TFR(17) TFR(29) TFR(16) TFR(24) x0 += K2;  x1 += 2u;
  TFR(13) TFR(15) TFR(26) TFR(6)  /*x0+=0*/  x1 += key + 3u;
  TFR(17) TFR(29) TFR(16) TFR(24) x0 += key; x1 += K2 + 4u;
  TFR(13) TFR(15) TFR(26) TFR(6)  x0 += K2;  x1 += 5u;
#undef TFR
  return x0 ^ x1;
}

// 16 keep draws for one 16q x 64k lane-tile (branch-free, 16-way ILP).
DEVI u32 keep16(u32 ib) {
  u32 m16 = 0;
  #pragma unroll
  for (int c = 0; c < 4; ++c) {
    #pragma unroll
    for (int r = 0; r < 4; ++r) {
      m16 |= (u32)(tf_bits(42u, ib + (u32)(r * 2048 + c * 16)) >= KEEPC) << (c * 4 + r);
    }
  }
  return m16;
}

// Wave-balanced dropout draws for the kept positions of m16 (validated r3).
// dwp = this wave's 256-slot LDS worklist. Same-wave LDS round trip, no barrier.
DEVI u32 drop_balanced(u32 m16, u32 wb, int lane, u16* dwp) {
  const int cnt = __popc(m16);
  int pre = cnt;
  #pragma unroll
  for (int dlt = 1; dlt < 64; dlt <<= 1) {
    int t = __shfl_up(pre, dlt);
    if (lane >= dlt) pre += t;
  }
  const int total = __shfl(pre, 63);   // wave total kept (~102, max ~145)
  pre -= cnt;                          // exclusive prefix = this lane's first slot
  {
    u32 mm = m16; int jj = pre;
    while (mm) {
      const u32 s = (u32)__builtin_ctz(mm); mm &= mm - 1u;
      dwp[jj] = (u16)(((u32)lane << 4) | s);
      ++jj;
    }
  }
  for (int ws2 = lane; ws2 < total; ws2 += 64) {
    const u32 e = (u32)dwp[ws2];
    const u32 oo = e >> 4, ss = e & 15u;
    const u32 ii = wb + ((oo >> 4) * 4u + (ss & 3u)) * 2048u + (oo & 15u) + (ss >> 2) * 16u;
    dwp[ws2] = (u16)(e | ((u32)(tf_bits(7u, ii) < DROPC) << 15));
  }
  u32 d16 = 0;
  {
    u32 mm = m16; int jj = pre;
    while (mm) {
      const u32 s = (u32)__builtin_ctz(mm); mm &= mm - 1u;
      d16 |= (u32)((dwp[jj] >> 15) & 1u) << s;
      ++jj;
    }
  }
  return d16;
}

// ---------------- QKV projection GEMM (x @ W.T + b), fp32 in, bf16 MFMA ----------------
// 64x64 tile / block, 4 waves (2x2), each wave 32x32 via 4 C-frags.
// LDS frag-major: chunk c = fragblk*64+lane holds T[row=fragblk*16+(lane&15)][k=(lane>>4)*8..+7]
__global__ __launch_bounds__(256) void proj_kernel(
    const float* __restrict__ Xq, const float* __restrict__ Xk, const float* __restrict__ Xv,
    const float* __restrict__ Wq, const float* __restrict__ Wk, const float* __restrict__ Wv,
    const float* __restrict__ bq, const float* __restrict__ bk, const float* __restrict__ bv,
    u16* __restrict__ Qo, u16* __restrict__ Ko, u16* __restrict__ Vto)
{
  const int z = blockIdx.z;
  const float* X = (z == 0) ? Xq : (z == 1) ? Xk : Xv;
  const float* W = (z == 0) ? Wq : (z == 1) ? Wk : Wv;
  const float* bias = (z == 0) ? bq : (z == 1) ? bk : bv;
  const int m0 = blockIdx.x * 64, n0 = blockIdx.y * 64;
  const int tid = threadIdx.x, w = tid >> 6, lane = tid & 63, l = lane & 15, quad = lane >> 4;

  __shared__ __align__(16) u16 lsA[2048], lsB[2048];

  const int srow = tid >> 2, skp = tid & 3;
  const int sc = ((srow >> 4) * 64 + skp * 16 + (srow & 15)) * 8;
  const float* gA = X + (u32)(m0 + srow) * DMODEL + skp * 8;
  const float* gB = W + (u32)(n0 + srow) * DMODEL + skp * 8;

  f32x4 acc[2][2] = {};
  const int mh = (w >> 1) * 2, nh = (w & 1) * 2;

  for (int k0 = 0; k0 < DMODEL; k0 += 32) {
    short8 av  = cvt8(*(const float4*)(gA + k0), *(const float4*)(gA + k0 + 4));
    short8 bv8 = cvt8(*(const float4*)(gB + k0), *(const float4*)(gB + k0 + 4));
    __syncthreads();
    *(short8*)(lsA + sc) = av;
    *(short8*)(lsB + sc) = bv8;
    __syncthreads();
    short8 a0 = *(const short8*)(lsA + ((mh + 0) * 64 + lane) * 8);
    short8 a1 = *(const short8*)(lsA + ((mh + 1) * 64 + lane) * 8);
    short8 b0 = *(const short8*)(lsB + ((nh + 0) * 64 + lane) * 8);
    short8 b1 = *(const short8*)(lsB + ((nh + 1) * 64 + lane) * 8);
    acc[0][0] = __builtin_amdgcn_mfma_f32_16x16x32_bf16(a0, b0, acc[0][0], 0, 0, 0);
    acc[0][1] = __builtin_amdgcn_mfma_f32_16x16x32_bf16(a0, b1, acc[0][1], 0, 0, 0);
    acc[1][0] = __builtin_amdgcn_mfma_f32_16x16x32_bf16(a1, b0, acc[1][0], 0, 0, 0);
    acc[1][1] = __builtin_amdgcn_mfma_f32_16x16x32_bf16(a1, b1, acc[1][1], 0, 0, 0);
  }

  #pragma unroll
  for (int ma = 0; ma < 2; ++ma) {
    #pragma unroll
    for (int nb = 0; nb < 2; ++nb) {
      const int n = n0 + (nh + nb) * 16 + l;
      const float bval = bias[n];
      const int h = n >> 6, d = n & 63;
      #pragma unroll
      for (int r = 0; r < 4; ++r) {
        const int m = m0 + (mh + ma) * 16 + quad * 4 + r;
        float val = acc[ma][nb][r] + bval;
        if (z == 0) val *= 0.125f;              // fold 1/sqrt(dk) into Q
        const int b = m >> 11, s = m & 2047;
        if (z == 0)      Qo [((u32)(b * NHEAD + h) * S_LEN + s) * DK + d] = f2bf(val);
        else if (z == 1) Ko [((u32)(b * NHEAD + h) * S_LEN + s) * DK + d] = f2bf(val);
        else             Vto[((u32)(b * NHEAD + h) * DK + d) * S_LEN + s] = f2bf(val); // V transposed
      }
    }
  }
}

// ---------------- flash attention, BARRIER-FREE 1-wave blocks ----------------
// Round-5 change: r4 proved in-wave scheduling can't fix the stalls -> they
// live at the 3 __syncthreads/tile (whole-CU drains) and at low effective
// occupancy under the serial threefry chains / divergent worklist loops.
// Nothing here needs a workgroup: K/V tiles are L2-resident (256 KB/bh,
// shared by 128 q-waves), P and the dropout worklist are wave-private.
// So: 64-thread blocks, ZERO barriers, K/V frags read directly from global
// in MFMA fragment layout (addresses = staging-map composed with frag-read
// map; each load touches 16 rows x 64B, lo/hi pair covers full 128B lines):
//   K B-frag (nc, lo): lane -> Ks[(bh*2048 + kt*64 + nc*16 + l)*64 + quad*8]
//   K B-frag (nc, hi): same + 32  (dk slots 4..7)
//   V B-frag (nd, lo): lane -> Vt[(bh*64 + nd*16 + l)*2048 + kt*64 + quad*8]
//   V B-frag (nd, hi): same + 32  (key slots 4..7)
// RNG (1200 instr) covers K-load latency; drop+softmax covers V-load latency.
__global__ __launch_bounds__(64) void attn_kernel(
    const u16* __restrict__ Qs, const u16* __restrict__ Ks, const u16* __restrict__ Vts,
    u16* __restrict__ ctx)
{
  const int bh = blockIdx.y;
  const int lane = threadIdx.x;                 // 1 wave per block
  const int l = lane & 15, quad = lane >> 4;
  const int qrow0 = blockIdx.x * 16;

  __shared__ __align__(16) u16 Pf[1024];        // 2 KB wave-private P frags
  __shared__ __align__(16) u16 dwb[256];        // 512 B dropout worklist

  // Q A-frags, preloaded (Q pre-scaled by 1/8)
  const u32 qbase = (u32)(bh * S_LEN + qrow0 + l) * DK + quad * 8;
  const short8 qa0 = *(const short8*)(Qs + qbase);
  const short8 qa1 = *(const short8*)(Qs + qbase + 32);

  // per-lane RNG base: rows start at qrow0+quad*4, col offset l (within tile)
  u32 ibase = ((u32)bh * 2048u + (u32)(qrow0 + quad * 4)) * 2048u + (u32)l;
  const u32 wb0 = ((u32)bh * 2048u + (u32)qrow0) * 2048u;

  f32x4 o[4] = {};
  float mr[4] = {NEG_INF, NEG_INF, NEG_INF, NEG_INF};
  float lr[4] = {0.f, 0.f, 0.f, 0.f};

  // direct frag-read bases (per-lane constant parts)
  const u16* kfb = Ks  + (u32)bh * (S_LEN * DK) + (u32)l * DK + quad * 8;
  const u16* vfb = Vts + (u32)bh * (DK * S_LEN) + (u32)l * S_LEN + quad * 8;

  // P staging addresses (XOR-swizzled, conflict-free; validated r2)
  const int hi = l >> 3, j = l & 7;
  const int pb  = (hi * 128 + quad * 32 + j) ^ (((quad >> 1) << 3) | (hi << 4));
  const int prd = (lane * 8) ^ (lane & 24);

  for (int kt = 0; kt < 32; ++kt) {
    // ---- K frags direct from global (L2-hot), consumed after keep16 ----
    const u16* kbt = kfb + (u32)kt * (64 * DK);
    short8 kf0 = *(const short8*)(kbt);
    short8 kf1 = *(const short8*)(kbt + 1024);
    short8 kf2 = *(const short8*)(kbt + 2048);
    short8 kf3 = *(const short8*)(kbt + 3072);
    short8 kg0 = *(const short8*)(kbt + 32);
    short8 kg1 = *(const short8*)(kbt + 1056);
    short8 kg2 = *(const short8*)(kbt + 2080);
    short8 kg3 = *(const short8*)(kbt + 3104);

    // ---- inline RNG: 16 keep draws (covers the K-load latency) ----
    const u32 m16 = keep16(ibase);
    ibase += 64u;

    // ---- S = Q K^T (16q x 64keys) ----
    f32x4 sc4[4];
    {
      f32x4 zz = {0.f, 0.f, 0.f, 0.f};
      zz = __builtin_amdgcn_mfma_f32_16x16x32_bf16(qa0, kf0, zz, 0, 0, 0);
      sc4[0] = __builtin_amdgcn_mfma_f32_16x16x32_bf16(qa1, kg0, zz, 0, 0, 0);
      zz = (f32x4){0.f, 0.f, 0.f, 0.f};
      zz = __builtin_amdgcn_mfma_f32_16x16x32_bf16(qa0, kf1, zz, 0, 0, 0);
      sc4[1] = __builtin_amdgcn_mfma_f32_16x16x32_bf16(qa1, kg1, zz, 0, 0, 0);
      zz = (f32x4){0.f, 0.f, 0.f, 0.f};
      zz = __builtin_amdgcn_mfma_f32_16x16x32_bf16(qa0, kf2, zz, 0, 0, 0);
      sc4[2] = __builtin_amdgcn_mfma_f32_16x16x32_bf16(qa1, kg2, zz, 0, 0, 0);
      zz = (f32x4){0.f, 0.f, 0.f, 0.f};
      zz = __builtin_amdgcn_mfma_f32_16x16x32_bf16(qa0, kf3, zz, 0, 0, 0);
      sc4[3] = __builtin_amdgcn_mfma_f32_16x16x32_bf16(qa1, kg3, zz, 0, 0, 0);
    }

    // ---- V frags direct from global; latency covered by drop+softmax ----
    const u16* vbt = vfb + (u32)kt * 64u;
    short8 vf[8];
    #pragma unroll
    for (int nd = 0; nd < 4; ++nd) {
      vf[2 * nd]     = *(const short8*)(vbt + nd * (16 * S_LEN));
      vf[2 * nd + 1] = *(const short8*)(vbt + nd * (16 * S_LEN) + 32);
    }

    const u32 d16 = drop_balanced(m16, wb0 + (u32)kt * 64u, lane, dwb);

    #pragma unroll
    for (int r = 0; r < 4; ++r) {
      float v0 = ((m16 >> (r + 0))  & 1u) ? sc4[0][r] : NEG_INF;
      float v1 = ((m16 >> (r + 4))  & 1u) ? sc4[1][r] : NEG_INF;
      float v2 = ((m16 >> (r + 8))  & 1u) ? sc4[2][r] : NEG_INF;
      float v3 = ((m16 >> (r + 12)) & 1u) ? sc4[3][r] : NEG_INF;
      float mx = fmaxf(fmaxf(v0, v1), fmaxf(v2, v3));
      mx = fmaxf(mx, __shfl_xor(mx, 1));
      mx = fmaxf(mx, __shfl_xor(mx, 2));
      mx = fmaxf(mx, __shfl_xor(mx, 4));
      mx = fmaxf(mx, __shfl_xor(mx, 8));
      const float mn = fmaxf(mr[r], mx);
      const float mnc = fmaxf(mn, -1e37f);        // clamp: exp(-inf-mnc)=0
      const float alpha = __expf(mr[r] - mnc);    // mr=-inf -> 0 (o,lr are 0)
      mr[r] = mn;
      const float p0 = __expf(v0 - mnc);
      const float p1 = __expf(v1 - mnc);
      const float p2 = __expf(v2 - mnc);
      const float p3 = __expf(v3 - mnc);
      float rs = p0 + p1 + p2 + p3;
      rs += __shfl_xor(rs, 1);
      rs += __shfl_xor(rs, 2);
      rs += __shfl_xor(rs, 4);
      rs += __shfl_xor(rs, 8);
      lr[r] = alpha * lr[r] + rs;
      o[0][r] = o[0][r] * alpha; o[1][r] = o[1][r] * alpha;
      o[2][r] = o[2][r] * alpha; o[3][r] = o[3][r] * alpha;
      // dropout (denominator uses undropped p; numerator uses p*dbit/0.9)
      const float pd0 = ((d16 >> (r + 0))  & 1u) ? p0 * (1.f / 0.9f) : 0.f;
      const float pd1 = ((d16 >> (r + 4))  & 1u) ? p1 * (1.f / 0.9f) : 0.f;
      const float pd2 = ((d16 >> (r + 8))  & 1u) ? p2 * (1.f / 0.9f) : 0.f;
      const float pd3 = ((d16 >> (r + 12)) & 1u) ? p3 * (1.f / 0.9f) : 0.f;
      // write P in A-frag layout (bank-conflict-free via XOR swizzle)
      const int pi = pb ^ (r * 8);
      Pf[pi      ] = f2bf(pd0);   // keys  0..15
      Pf[pi + 256] = f2bf(pd1);   // keys 16..31
      Pf[pi + 512] = f2bf(pd2);   // keys 32..47
      Pf[pi + 768] = f2bf(pd3);   // keys 48..63
    }
    // same-wave LDS round-trip: read P as A-frags (swizzled chunk order)
    short8 pa0 = *(const short8*)(Pf + prd);
    short8 pa1 = *(const short8*)(Pf + 512 + prd);
    #pragma unroll
    for (int nd = 0; nd < 4; ++nd) {
      o[nd] = __builtin_amdgcn_mfma_f32_16x16x32_bf16(pa0, vf[2 * nd],     o[nd], 0, 0, 0);
      o[nd] = __builtin_amdgcn_mfma_f32_16x16x32_bf16(pa1, vf[2 * nd + 1], o[nd], 0, 0, 0);
    }
  }

  const int b = bh >> 4, h = bh & 15;
  #pragma unroll
  for (int r = 0; r < 4; ++r) {
    const float inv = 1.f / lr[r];
    const int qrow = qrow0 + quad * 4 + r;
    const u32 ob = (u32)(b * S_LEN + qrow) * DMODEL + h * DK;
    ctx[ob + 0  + l] = f2bf(o[0][r] * inv);
    ctx[ob + 16 + l] = f2bf(o[1][r] * inv);
    ctx[ob + 32 + l] = f2bf(o[2][r] * inv);
    ctx[ob + 48 + l] = f2bf(o[3][r] * inv);
  }
}

// ---------------- output projection (ctx @ Wo.T + bo), bf16 A, fp32 B-in, fp32 out ----------------
__global__ __launch_bounds__(256) void oproj_kernel(
    const u16* __restrict__ X, const float* __restrict__ W, const float* __restrict__ bias,
    float* __restrict__ out)
{
  const int m0 = blockIdx.x * 64, n0 = blockIdx.y * 64;
  const int tid = threadIdx.x, w = tid >> 6, lane = tid & 63, l = lane & 15, quad = lane >> 4;

  __shared__ __align__(16) u16 lsA[2048], lsB[2048];

  const int srow = tid >> 2, skp = tid & 3;
  const int sc = ((srow >> 4) * 64 + skp * 16 + (srow & 15)) * 8;
  const u16*  gA = X + (u32)(m0 + srow) * DMODEL + skp * 8;
  const float* gB = W + (u32)(n0 + srow) * DMODEL + skp * 8;

  f32x4 acc[2][2] = {};
  const int mh = (w >> 1) * 2, nh = (w & 1) * 2;

  for (int k0 = 0; k0 < DMODEL; k0 += 32) {
    short8 av  = *(const short8*)(gA + k0);
    short8 bv8 = cvt8(*(const float4*)(gB + k0), *(const float4*)(gB + k0 + 4));
    __syncthreads();
    *(short8*)(lsA + sc) = av;
    *(short8*)(lsB + sc) = bv8;
    __syncthreads();
    short8 a0 = *(const short8*)(lsA + ((mh + 0) * 64 + lane) * 8);
    short8 a1 = *(const short8*)(lsA + ((mh + 1) * 64 + lane) * 8);
    short8 b0 = *(const short8*)(lsB + ((nh + 0) * 64 + lane) * 8);
    short8 b1 = *(const short8*)(lsB + ((nh + 1) * 64 + lane) * 8);
    acc[0][0] = __builtin_amdgcn_mfma_f32_16x16x32_bf16(a0, b0, acc[0][0], 0, 0, 0);
    acc[0][1] = __builtin_amdgcn_mfma_f32_16x16x32_bf16(a0, b1, acc[0][1], 0, 0, 0);
    acc[1][0] = __builtin_amdgcn_mfma_f32_16x16x32_bf16(a1, b0, acc[1][0], 0, 0, 0);
    acc[1][1] = __builtin_amdgcn_mfma_f32_16x16x32_bf16(a1, b1, acc[1][1], 0, 0, 0);
  }

  #pragma unroll
  for (int ma = 0; ma < 2; ++ma) {
    #pragma unroll
    for (int nb = 0; nb < 2; ++nb) {
      const int n = n0 + (nh + nb) * 16 + l;
      const float bval = bias[n];
      #pragma unroll
      for (int r = 0; r < 4; ++r) {
        const int m = m0 + (mh + ma) * 16 + quad * 4 + r;
        out[(u32)m * DMODEL + n] = acc[ma][nb][r] + bval;
      }
    }
  }
}

extern "C" void kernel_launch(void* const* d_in, const int* in_sizes, int n_in,
                              void* d_out, int out_size, void* d_ws, size_t ws_size,
                              hipStream_t stream) {
  (void)in_sizes; (void)n_in; (void)out_size; (void)ws_size;
  const float* q  = (const float*)d_in[0];
  const float* k  = (const float*)d_in[1];
  const float* v  = (const float*)d_in[2];
  const float* Wq = (const float*)d_in[3];
  const float* bq = (const float*)d_in[4];
  const float* Wk = (const float*)d_in[5];
  const float* bk = (const float*)d_in[6];
  const float* Wv = (const float*)d_in[7];
  const float* bv = (const float*)d_in[8];
  const float* Wo = (const float*)d_in[9];
  const float* bo = (const float*)d_in[10];

  char* ws = (char*)d_ws;
  u16* Qs   = (u16*)(ws);                 // [bh][s][dk] bf16, pre-scaled 1/8 (16 MB)
  u16* Ks   = (u16*)(ws + 16777216);      // [bh][s][dk]
  u16* Vts  = (u16*)(ws + 33554432);      // [bh][dk][s]  (transposed)
  u16* ctx  = (u16*)(ws + 50331648);      // [b][s][h*dk]  (total ws: 64 MB)

  proj_kernel<<<dim3(128, 16, 3), 256, 0, stream>>>(q, k, v, Wq, Wk, Wv,
                                                    bq, bk, bv, Qs, Ks, Vts);
  attn_kernel<<<dim3(128, 64), 64, 0, stream>>>(Qs, Ks, Vts, ctx);
  oproj_kernel<<<dim3(128, 16), 256, 0, stream>>>(ctx, Wo, bo, (float*)d_out);
}